// Round 17
// baseline (201.202 us; speedup 1.0000x reference)
//
#include <hip/hip_runtime.h>
#include <hip/hip_bf16.h>

#define CDIM   1024
#define NHEADS 16
#define DHEAD  64
#define BATCH  4
#define TSEQ   2048
#define MROWS  (BATCH * TSEQ)
#define QSTR   3072                /* fused qkv row stride */
#define NEG_BIG (-1e30f)
#define MASKVAL (-3.0e38f)
#define SCALE_L2E 0.18033688011f   /* 0.125 * log2(e) */
#define DEFER_TH 11.5416f          /* 8 nats in log2 units */

typedef __attribute__((ext_vector_type(8)))  short bf16x8;
typedef __attribute__((ext_vector_type(4)))  float f32x4;
typedef __attribute__((ext_vector_type(16))) float f32x16;

__device__ __forceinline__ unsigned short f2bf(float f) {
    __hip_bfloat16 h = __float2bfloat16(f);
    return *reinterpret_cast<unsigned short*>(&h);
}
__device__ __forceinline__ unsigned int cvtpk(float a, float b) {
    unsigned r;
    asm("v_cvt_pk_bf16_f32 %0, %1, %2" : "=v"(r) : "v"(a), "v"(b));
    return r;   // lo = bf16(a), hi = bf16(b)
}
__device__ __forceinline__ float ex2(float x) {   // raw v_exp_f32 (exp2)
    float r; asm("v_exp_f32 %0, %1" : "=v"(r) : "v"(x)); return r;
}

// ---------------- fused prep: x->bf16, 4x W->W^T bf16, bias concat ----------
__global__ __launch_bounds__(256)
void prep_kernel(const float* __restrict__ x,
                 const float* __restrict__ Wq, const float* __restrict__ Wk,
                 const float* __restrict__ Wv, const float* __restrict__ Wp,
                 const float* __restrict__ bq, const float* __restrict__ bk,
                 const float* __restrict__ bv,
                 unsigned short* __restrict__ xb,
                 unsigned short* __restrict__ Tq, unsigned short* __restrict__ Tk,
                 unsigned short* __restrict__ Tv, unsigned short* __restrict__ Tp,
                 float* __restrict__ bias3)
{
    const int z = blockIdx.z, t = threadIdx.x;
    if (z < 4) {
        const float* W; unsigned short* T;
        switch (z) {
            case 0:  W = Wq; T = Tq; break;
            case 1:  W = Wk; T = Tk; break;
            case 2:  W = Wv; T = Tv; break;
            default: W = Wp; T = Tp; break;
        }
        __shared__ float tile[32][33];
        const int r = t >> 3;
        const int c4 = (t & 7) * 4;
        const int n0 = blockIdx.x * 32, k0 = blockIdx.y * 32;
        float4 v = *reinterpret_cast<const float4*>(&W[(size_t)(k0 + r) * CDIM + n0 + c4]);
        tile[r][c4 + 0] = v.x; tile[r][c4 + 1] = v.y;
        tile[r][c4 + 2] = v.z; tile[r][c4 + 3] = v.w;
        __syncthreads();
        uint2 o;
        o.x = (unsigned)f2bf(tile[c4 + 0][r]) | ((unsigned)f2bf(tile[c4 + 1][r]) << 16);
        o.y = (unsigned)f2bf(tile[c4 + 2][r]) | ((unsigned)f2bf(tile[c4 + 3][r]) << 16);
        *reinterpret_cast<uint2*>(&T[(size_t)(n0 + r) * CDIM + k0 + c4]) = o;
    } else {
        const int chunk = z - 4;
        size_t i = ((size_t)(chunk * 1024 + blockIdx.y * 32 + blockIdx.x) * 256 + t);
        const float4* p = reinterpret_cast<const float4*>(x) + i * 2;
        float4 a = p[0], b = p[1];
        uint4 o;
        o.x = (unsigned)f2bf(a.x) | ((unsigned)f2bf(a.y) << 16);
        o.y = (unsigned)f2bf(a.z) | ((unsigned)f2bf(a.w) << 16);
        o.z = (unsigned)f2bf(b.x) | ((unsigned)f2bf(b.y) << 16);
        o.w = (unsigned)f2bf(b.z) | ((unsigned)f2bf(b.w) << 16);
        *reinterpret_cast<uint4*>(xb + i * 8) = o;
        if (chunk == 0 && blockIdx.y == 0 && blockIdx.x < 12) {
            int j = blockIdx.x * 256 + t;   // 0..3071
            float v = (j < 1024) ? bq[j] : (j < 2048 ? bk[j - 1024] : bv[j - 2048]);
            bias3[j] = v;
        }
    }
}

// ======== 3-buffer counted-vmcnt pipelined GEMM (T3+T4, asym tiles) =========
// (R14-verified. vmcnt(6) counted; see R14 derivation.)
#define GBAR8  asm volatile("s_barrier" ::: "memory")
#define LGKM0  asm volatile("s_waitcnt lgkmcnt(0)" ::: "memory")
#define VMC6   asm volatile("s_waitcnt vmcnt(6)" ::: "memory")
#define VMC0   asm volatile("s_waitcnt vmcnt(0)" ::: "memory")

#define STAGE8(bufp, off, srcp) do { \
    __builtin_amdgcn_global_load_lds( \
        (const __attribute__((address_space(1))) void*)(srcp), \
        (__attribute__((address_space(3))) void*)((bufp) + (off) + wv * 1024), 16, 0, 0); \
    __builtin_amdgcn_global_load_lds( \
        (const __attribute__((address_space(1))) void*)((srcp) + 65536), \
        (__attribute__((address_space(3))) void*)((bufp) + (off) + 8192 + wv * 1024), 16, 0, 0); \
} while (0)

#define LDA_ALL(Ab) do { \
    _Pragma("unroll") for (int m_ = 0; m_ < 4; ++m_) { \
        const int rl_ = wr * 64 + m_ * 16 + lj; \
        _Pragma("unroll") for (int k_ = 0; k_ < 2; ++k_) \
            af[m_][k_] = *reinterpret_cast<const bf16x8*>( \
                (Ab) + rl_ * 128 + (((k_ * 4 + lg) ^ (lj & 7)) * 16)); \
    } } while (0)

#define LDB_PAIR(Bb, pairi) do { \
    _Pragma("unroll") for (int n_ = 0; n_ < 2; ++n_) { \
        const int rl_ = wc * 64 + ((pairi) * 2 + n_) * 16 + lj; \
        _Pragma("unroll") for (int k_ = 0; k_ < 2; ++k_) \
            bfr[n_][k_] = *reinterpret_cast<const bf16x8*>( \
                (Bb) + rl_ * 128 + (((k_ * 4 + lg) ^ (lj & 7)) * 16)); \
    } } while (0)

#define MM_PAIR(npair) do { \
    __builtin_amdgcn_s_setprio(1); \
    _Pragma("unroll") for (int m_ = 0; m_ < 4; ++m_) \
        _Pragma("unroll") for (int n_ = 0; n_ < 2; ++n_) \
            _Pragma("unroll") for (int k_ = 0; k_ < 2; ++k_) \
                acc[m_][(npair) * 2 + n_] = \
                    __builtin_amdgcn_mfma_f32_16x16x32_bf16( \
                        af[m_][k_], bfr[n_][k_], acc[m_][(npair) * 2 + n_], 0, 0, 0); \
    __builtin_amdgcn_s_setprio(0); \
} while (0)

template<int BM, int BN, int OUTMODE>
__global__ __launch_bounds__(512)
void gemm_8ph3(const unsigned short* __restrict__ A,
               const unsigned short* __restrict__ BT,
               const float* __restrict__ bias,
               void* __restrict__ Cout, int N, int nScaled)
{
    constexpr int WN = BN / 64;
    constexpr bool A_SMALL = (BM == 128);
    constexpr int AOFF = 0;
    constexpr int BOFF = BM * 128;
    constexpr int SOFF   = A_SMALL ? AOFF : BOFF;
    constexpr int LLOOFF = A_SMALL ? BOFF : AOFF;
    constexpr int LHIOFF = LLOOFF + 16384;
    constexpr int BUFSZ  = (BM + BN) * 128;     // 49152 bytes

    __shared__ __align__(16) char lds8[3 * BUFSZ];   // 144 KB
    const int tid = threadIdx.x;
    const int nbn = N / BN;
    const int bid = blockIdx.x;
    const int wg  = (bid & 7) * ((int)gridDim.x >> 3) + (bid >> 3);  // XCD swizzle
    const int n0  = (wg % nbn) * BN;
    const int m0  = (wg / nbn) * BM;

    const int lane = tid & 63, wv = tid >> 6;
    const int wr = wv / WN, wc = wv % WN;
    const int lj = lane & 15, lg = lane >> 4;
    const int srow = tid >> 3;
    const int gsw  = 8 * ((tid & 7) ^ ((tid >> 3) & 7));

    const unsigned short* Sm  = A_SMALL ? A : BT;
    const int             sb  = A_SMALL ? m0 : n0;
    const unsigned short* Lm  = A_SMALL ? BT : A;
    const int             lb  = A_SMALL ? n0 : m0;
    const unsigned short* Ss  = Sm + (size_t)(sb + srow) * 1024 + gsw;
    const unsigned short* Llo = Lm + (size_t)(lb + srow) * 1024 + gsw;
    const unsigned short* Lhi = Lm + (size_t)(lb + 128 + srow) * 1024 + gsw;

    f32x4 acc[4][4];
    #pragma unroll
    for (int i = 0; i < 4; ++i)
        #pragma unroll
        for (int j = 0; j < 4; ++j) acc[i][j] = f32x4{0.f, 0.f, 0.f, 0.f};

    char* bufA = &lds8[0];
    char* bufB = &lds8[BUFSZ];
    char* bufC = &lds8[2 * BUFSZ];

    STAGE8(bufA, SOFF,   Ss);
    STAGE8(bufA, LLOOFF, Llo);
    STAGE8(bufA, LHIOFF, Lhi);
    STAGE8(bufB, SOFF,   Ss  + 64);
    STAGE8(bufB, LLOOFF, Llo + 64);
    STAGE8(bufB, LHIOFF, Lhi + 64);
    VMC6; GBAR8;

    bf16x8 af[4][2], bfr[2][2];

    for (int t = 0; t < 16; ++t) {
        const bool st = (t + 2) < 16;
        const int  t2 = (t + 2) * 64;

        LDA_ALL(bufA + AOFF); LDB_PAIR(bufA + BOFF, 0);
        if (st) {
            STAGE8(bufC, SOFF,   Ss  + t2);
            STAGE8(bufC, LLOOFF, Llo + t2);
        }
        GBAR8; LGKM0; MM_PAIR(0); GBAR8;

        LDB_PAIR(bufA + BOFF, 1);
        if (st) STAGE8(bufC, LHIOFF, Lhi + t2);
        GBAR8; LGKM0; MM_PAIR(1);
        if (st) { VMC6; } else { VMC0; }
        GBAR8;

        char* tmp = bufA; bufA = bufB; bufB = bufC; bufC = tmp;
    }

    const float sc = (OUTMODE == 0 && n0 < nScaled) ? SCALE_L2E : 1.0f;
    float bcol[4];
    #pragma unroll
    for (int nr = 0; nr < 4; ++nr) bcol[nr] = bias[n0 + wc * 64 + nr * 16 + lj];

    #pragma unroll
    for (int mr = 0; mr < 4; ++mr) {
        #pragma unroll
        for (int r4 = 0; r4 < 4; ++r4) {
            const int row = m0 + wr * 64 + mr * 16 + lg * 4 + r4;
            #pragma unroll
            for (int nr = 0; nr < 4; ++nr) {
                const int col = n0 + wc * 64 + nr * 16 + lj;
                float v = (acc[mr][nr][r4] + bcol[nr]) * sc;
                if (OUTMODE == 0)
                    reinterpret_cast<unsigned short*>(Cout)[(size_t)row * N + col] = f2bf(v);
                else
                    reinterpret_cast<float*>(Cout)[(size_t)row * N + col] = v;
            }
        }
    }
}

// ---------------- MFMA flash attention: MFMA row-sum (ones trick) -----------
// R16 dbuf body. VALU diet round 2: row-sum tree replaced by one extra MFMA
// per PV_STEP with an all-ones A-fragment: ys = mfma(1,P^T,ys) -> every
// output row equals sum_k P[q][k] for col q (C-layout col=lane&31 => both
// hi-halves identical; no shfl). Denominator sums the SAME bf16 P as the
// numerator. Rescale scales ys (defer-rare). Max tree in max3-friendly form.
// DO NOT: min-waves bound (R8 spill), KVBLK=128 (R12 spill), 1024-block
// remap (R11), 2-deep S (R6). Spill canary: WRITE_SIZE must stay ~16KB.
#define PV_STEP(m, T, rb) { \
    unsigned int w01 = cvtpk(T[(rb)+0], T[(rb)+1]); \
    unsigned int w23 = cvtpk(T[(rb)+2], T[(rb)+3]); \
    unsigned int w45 = cvtpk(T[(rb)+4], T[(rb)+5]); \
    unsigned int w67 = cvtpk(T[(rb)+6], T[(rb)+7]); \
    asm("v_permlane32_swap_b32 %0, %1" : "+v"(w01), "+v"(w45)); \
    asm("v_permlane32_swap_b32 %0, %1" : "+v"(w23), "+v"(w67)); \
    union { unsigned int u[4]; bf16x8 v; } pa; \
    pa.u[0] = w01; pa.u[1] = w23; pa.u[2] = w45; pa.u[3] = w67; \
    const int voff = (32 * (m) + 16 * hi) ^ lqswz; \
    bf16x8 va = *reinterpret_cast<const bf16x8*>(VTB + lq * 128 + voff); \
    bf16x8 vb = *reinterpret_cast<const bf16x8*>(VTB + (lq + 32) * 128 + voff); \
    y0 = __builtin_amdgcn_mfma_f32_32x32x16_bf16(va, pa.v, y0, 0, 0, 0); \
    y1 = __builtin_amdgcn_mfma_f32_32x32x16_bf16(vb, pa.v, y1, 0, 0, 0); \
    ys = __builtin_amdgcn_mfma_f32_32x32x16_bf16(onesf, pa.v, ys, 0, 0, 0); \
}

#define VPACK() do { \
    pk[0] = __builtin_amdgcn_perm(vtb.x, vta.x, 0x05040100u); \
    pk[1] = __builtin_amdgcn_perm(vtb.x, vta.x, 0x07060302u); \
    pk[2] = __builtin_amdgcn_perm(vtb.y, vta.y, 0x05040100u); \
    pk[3] = __builtin_amdgcn_perm(vtb.y, vta.y, 0x07060302u); \
    pk[4] = __builtin_amdgcn_perm(vtb.z, vta.z, 0x05040100u); \
    pk[5] = __builtin_amdgcn_perm(vtb.z, vta.z, 0x07060302u); \
    pk[6] = __builtin_amdgcn_perm(vtb.w, vta.w, 0x05040100u); \
    pk[7] = __builtin_amdgcn_perm(vtb.w, vta.w, 0x07060302u); \
} while (0)

__global__ __launch_bounds__(256)
void attn_mfma6(const unsigned short* __restrict__ QKV, unsigned short* __restrict__ Yb)
{
    __shared__ __align__(16) char KV[2][16384];   // [buf][K 8KB | V^T 8KB]
    __shared__ unsigned short Ysc[4][32 * 72];    // per-wave [q][d], 144B stride

    const int tid = threadIdx.x, lane = tid & 63, wid = tid >> 6;
    const int lq = lane & 31, hi = lane >> 5;
    const int lqswz = (lq & 7) << 4;

    // all-ones bf16 A-fragment (1.0 = 0x3F80)
    union { unsigned int u[4]; bf16x8 v; } ones_;
    ones_.u[0] = 0x3F803F80u; ones_.u[1] = 0x3F803F80u;
    ones_.u[2] = 0x3F803F80u; ones_.u[3] = 0x3F803F80u;
    const bf16x8 onesf = ones_.v;

    // XCD-grouped decomposition: id%8 == hb%8 -> same (h,b) shares an XCD
    const int id  = blockIdx.x;
    const int kk  = id >> 3;
    const int hb  = (id & 7) + 8 * (kk >> 3);
    const int pair = kk & 7;
    const int h = hb & 15, bz = hb >> 4;

    const size_t rowbase = (size_t)bz * TSEQ;
    const int hq = h * DHEAD, hk = 1024 + h * DHEAD, hv = 2048 + h * DHEAD;

    // staging thread mapping (constant per thread)
    const int krow = tid >> 3;           // K rows krow, krow+32
    const int kswz = ((tid & 7) * 16) ^ ((krow & 7) << 4);
    const int vk2  = 2 * (tid & 31);     // V key-pair
    const int vdg  = (tid >> 5) * 8;     // V d-group
    const int vkb  = vk2 * 2;            // byte offset of pair

    for (int iter = 0; iter < 2; ++iter) {
        const int qtile = iter ? (15 - pair) : pair;
        const int q0 = qtile * 128;
        const int wq = q0 + wid * 32;

        bf16x8 qf[4];                            // Q^T B-frags: d = 16s + 8hi + j
        {
            const unsigned short* qp = QKV + (rowbase + wq + lq) * QSTR + hq + hi * 8;
            #pragma unroll
            for (int s = 0; s < 4; ++s)
                qf[s] = *reinterpret_cast<const bf16x8*>(qp + s * 16);
        }
        f32x16 y0, y1, ys;                       // Y^T tiles + MFMA row-sum
        #pragma unroll
        for (int r = 0; r < 16; ++r) { y0[r] = 0.f; y1[r] = 0.f; ys[r] = 0.f; }
        float mrow = NEG_BIG;

        const int ktend = 2 * qtile + 2;

        // prefetch tile 0 into registers; pack V immediately (prologue only)
        uint4 kr0, kr1, vta, vtb;
        unsigned pk[8];
        {
            const unsigned short* kp = QKV + (rowbase + krow) * QSTR + hk + (tid & 7) * 8;
            kr0 = *reinterpret_cast<const uint4*>(kp);
            kr1 = *reinterpret_cast<const uint4*>(kp + 32 * QSTR);
            const unsigned short* vp = QKV + (rowbase + vk2) * QSTR + hv + vdg;
            vta = *reinterpret_cast<const uint4*>(vp);
            vtb = *reinterpret_cast<const uint4*>(vp + QSTR);
            VPACK();
        }

        for (int kt = 0; kt < ktend; ++kt) {
            char* KsB = &KV[kt & 1][0];
            char* VTB = &KV[kt & 1][8192];
            // ---- write prefetched regs -> buf[kt&1] (dbuf, single barrier)
            *reinterpret_cast<uint4*>(KsB + krow * 128 + kswz) = kr0;
            *reinterpret_cast<uint4*>(KsB + (krow + 32) * 128 + kswz) = kr1;
            #pragma unroll
            for (int i2 = 0; i2 < 8; ++i2) {
                const int d = vdg + i2;
                *reinterpret_cast<unsigned*>(VTB + d * 128 + (vkb ^ ((d & 7) << 4))) = pk[i2];
            }
            __syncthreads();                     // single barrier per tile

            // ---- issue next tile's global loads (latency hides under compute)
            const bool more = (kt + 1 < ktend);
            if (more) {
                const unsigned short* kp = QKV + (rowbase + (kt + 1) * 64 + krow) * QSTR + hk + (tid & 7) * 8;
                kr0 = *reinterpret_cast<const uint4*>(kp);
                kr1 = *reinterpret_cast<const uint4*>(kp + 32 * QSTR);
                const unsigned short* vp = QKV + (rowbase + (kt + 1) * 64 + vk2) * QSTR + hv + vdg;
                vta = *reinterpret_cast<const uint4*>(vp);
                vtb = *reinterpret_cast<const uint4*>(vp + QSTR);
            }

            if (kt * 64 <= wq + 31) {            // tile intersects this wave's rows
                // ---- S^T = K Q^T (8 mfma 32x32x16); scale pre-folded into Q
                f32x16 s0, s1;
                #pragma unroll
                for (int r = 0; r < 16; ++r) { s0[r] = 0.f; s1[r] = 0.f; }
                #pragma unroll
                for (int s = 0; s < 4; ++s) {
                    const int off = (s * 32 + hi * 16) ^ lqswz;
                    bf16x8 k0 = *reinterpret_cast<const bf16x8*>(KsB + lq * 128 + off);
                    bf16x8 k1 = *reinterpret_cast<const bf16x8*>(KsB + (lq + 32) * 128 + off);
                    s0 = __builtin_amdgcn_mfma_f32_32x32x16_bf16(k0, qf[s], s0, 0, 0, 0);
                    s1 = __builtin_amdgcn_mfma_f32_32x32x16_bf16(k1, qf[s], s1, 0, 0, 0);
                }

                // ---- causal mask (diagonal tiles only)
                const bool diag = (kt * 64 + 63) > wq;
                if (diag) {
                    const int q_own = wq + lq;
                    #pragma unroll
                    for (int r = 0; r < 16; ++r) {
                        const int kl = kt * 64 + (r & 3) + 8 * (r >> 2) + 4 * hi;
                        if (kl > q_own) s0[r] = MASKVAL;
                        if (kl + 32 > q_own) s1[r] = MASKVAL;
                    }
                }

                // ---- row max, max3-friendly nesting + pair exchange
                float t8[8];
                #pragma unroll
                for (int r = 0; r < 8; ++r)
                    t8[r] = fmaxf(fmaxf(fmaxf(s0[r], s0[r + 8]), s1[r]), s1[r + 8]);
                float pm = fmaxf(
                    fmaxf(fmaxf(t8[0], t8[1]), fmaxf(t8[2], t8[3])),
                    fmaxf(fmaxf(t8[4], t8[5]), fmaxf(t8[6], t8[7])));
                pm = fmaxf(pm, __shfl_xor(pm, 32));

                // ---- defer-max rescale (T13): scale y0,y1,ys together
                if (__any(pm > mrow + DEFER_TH)) {
                    const float mnew = fmaxf(mrow, pm);
                    const float alpha = ex2(mrow - mnew);
                    #pragma unroll
                    for (int r = 0; r < 16; ++r) {
                        y0[r] *= alpha; y1[r] *= alpha; ys[r] *= alpha;
                    }
                    mrow = mnew;
                }
                // ---- exp2 (row-sum now via ones-MFMA in PV_STEP)
                #pragma unroll
                for (int r = 0; r < 16; ++r) {
                    s0[r] = ex2(s0[r] - mrow);
                    s1[r] = ex2(s1[r] - mrow);
                }

                // ---- Y^T += V^T P^T (8+4 mfma, incl. ys row-sum)
                PV_STEP(0, s0, 0)
                PV_STEP(1, s0, 8)
                PV_STEP(2, s1, 0)
                PV_STEP(3, s1, 8)
            }

            // ---- pack next tile's V (load-waits satisfied; outside write window)
            if (more) VPACK();
        }

        // ---- epilogue: normalize, transpose via per-wave LDS, coalesced store
        {
            const float inv = 1.f / ys[0];       // all ys rows equal = sum_k P
            char* ysb = (char*)&Ysc[wid][0];
            #pragma unroll
            for (int t = 0; t < 8; ++t) {
                const int dl = ((2 * t) & 3) + 8 * (t >> 1) + 4 * hi;
                unsigned int wa = cvtpk(y0[2 * t] * inv, y0[2 * t + 1] * inv);
                unsigned int wb = cvtpk(y1[2 * t] * inv, y1[2 * t + 1] * inv);
                *reinterpret_cast<unsigned int*>(ysb + lq * 144 + dl * 2) = wa;
                *reinterpret_cast<unsigned int*>(ysb + lq * 144 + (dl + 32) * 2) = wb;
            }
            #pragma unroll
            for (int u = 0; u < 4; ++u) {
                const int rr = lane >> 1, ch = (lane & 1) + 2 * u;
                uint4 val = *reinterpret_cast<const uint4*>(ysb + rr * 144 + ch * 16);
                *reinterpret_cast<uint4*>(Yb + (rowbase + q0 + wid * 32 + rr) * CDIM + h * DHEAD + ch * 8) = val;
            }
        }
    }
}

// ---------------------------------------------------------------------------
extern "C" void kernel_launch(void* const* d_in, const int* in_sizes, int n_in,
                              void* d_out, int out_size, void* d_ws, size_t ws_size,
                              hipStream_t stream)
{
    const float* x  = (const float*)d_in[0];
    const float* Wk = (const float*)d_in[1];
    const float* bk = (const float*)d_in[2];
    const float* Wq = (const float*)d_in[3];
    const float* bq = (const float*)d_in[4];
    const float* Wv = (const float*)d_in[5];
    const float* bv = (const float*)d_in[6];
    const float* Wp = (const float*)d_in[7];
    const float* bp = (const float*)d_in[8];

    const size_t xe = (size_t)MROWS * CDIM;   // 8,388,608
    const size_t we = (size_t)CDIM * CDIM;    // 1,048,576
    unsigned short* xb    = (unsigned short*)d_ws;
    unsigned short* wqkvt = xb + xe;          // [3072][1024] = Wq^T|Wk^T|Wv^T
    unsigned short* wpt   = wqkvt + 3 * we;
    unsigned short* qkv   = wpt + we;         // [8192][3072] bf16
    unsigned short* ab    = qkv + (size_t)MROWS * QSTR;
    float*          bias3 = (float*)(ab + xe);

    // fused prep: x->bf16, W^T x4, bias concat (one launch)
    prep_kernel<<<dim3(32, 32, 8), 256, 0, stream>>>(
        x, Wq, Wk, Wv, Wp, bq, bk, bv,
        xb, wqkvt, wqkvt + we, wqkvt + 2 * we, wpt, bias3);

    // fused QKV projection: 128x256 3-buf counted pipeline, 768 blocks (3 rounds)
    gemm_8ph3<128, 256, 0><<<768, 512, 0, stream>>>(xb, wqkvt, bias3, qkv,
                                                    QSTR, 1024);

    attn_mfma6<<<512, 256, 0, stream>>>(qkv, ab);

    // output projection -> fp32: 256x128 3-buf counted pipeline, 256 blocks (1 round)
    gemm_8ph3<256, 128, 1><<<256, 512, 0, stream>>>(ab, wpt, bp, d_out,
                                                    CDIM, 0);
}

// Round 18
// 163.033 us; speedup vs baseline: 1.2341x; 1.2341x over previous
//
#include <hip/hip_runtime.h>
#include <hip/hip_bf16.h>

#define CDIM   1024
#define NHEADS 16
#define DHEAD  64
#define BATCH  4
#define TSEQ   2048
#define MROWS  (BATCH * TSEQ)
#define QSTR   3072                /* fused qkv row stride */
#define NEG_BIG (-1e30f)
#define MASKVAL (-3.0e38f)
#define SCALE_L2E 0.18033688011f   /* 0.125 * log2(e) */
#define DEFER_TH 11.5416f          /* 8 nats in log2 units */

typedef __attribute__((ext_vector_type(8)))  short bf16x8;
typedef __attribute__((ext_vector_type(4)))  float f32x4;
typedef __attribute__((ext_vector_type(16))) float f32x16;

__device__ __forceinline__ unsigned short f2bf(float f) {
    __hip_bfloat16 h = __float2bfloat16(f);
    return *reinterpret_cast<unsigned short*>(&h);
}
__device__ __forceinline__ unsigned int cvtpk(float a, float b) {
    unsigned r;
    asm("v_cvt_pk_bf16_f32 %0, %1, %2" : "=v"(r) : "v"(a), "v"(b));
    return r;   // lo = bf16(a), hi = bf16(b)
}
__device__ __forceinline__ float ex2(float x) {   // raw v_exp_f32 (exp2)
    float r; asm("v_exp_f32 %0, %1" : "=v"(r) : "v"(x)); return r;
}

// ---------------- fused prep: x->bf16, 4x W->W^T bf16, bias concat ----------
__global__ __launch_bounds__(256)
void prep_kernel(const float* __restrict__ x,
                 const float* __restrict__ Wq, const float* __restrict__ Wk,
                 const float* __restrict__ Wv, const float* __restrict__ Wp,
                 const float* __restrict__ bq, const float* __restrict__ bk,
                 const float* __restrict__ bv,
                 unsigned short* __restrict__ xb,
                 unsigned short* __restrict__ Tq, unsigned short* __restrict__ Tk,
                 unsigned short* __restrict__ Tv, unsigned short* __restrict__ Tp,
                 float* __restrict__ bias3)
{
    const int z = blockIdx.z, t = threadIdx.x;
    if (z < 4) {
        const float* W; unsigned short* T;
        switch (z) {
            case 0:  W = Wq; T = Tq; break;
            case 1:  W = Wk; T = Tk; break;
            case 2:  W = Wv; T = Tv; break;
            default: W = Wp; T = Tp; break;
        }
        __shared__ float tile[32][33];
        const int r = t >> 3;
        const int c4 = (t & 7) * 4;
        const int n0 = blockIdx.x * 32, k0 = blockIdx.y * 32;
        float4 v = *reinterpret_cast<const float4*>(&W[(size_t)(k0 + r) * CDIM + n0 + c4]);
        tile[r][c4 + 0] = v.x; tile[r][c4 + 1] = v.y;
        tile[r][c4 + 2] = v.z; tile[r][c4 + 3] = v.w;
        __syncthreads();
        uint2 o;
        o.x = (unsigned)f2bf(tile[c4 + 0][r]) | ((unsigned)f2bf(tile[c4 + 1][r]) << 16);
        o.y = (unsigned)f2bf(tile[c4 + 2][r]) | ((unsigned)f2bf(tile[c4 + 3][r]) << 16);
        *reinterpret_cast<uint2*>(&T[(size_t)(n0 + r) * CDIM + k0 + c4]) = o;
    } else {
        const int chunk = z - 4;
        size_t i = ((size_t)(chunk * 1024 + blockIdx.y * 32 + blockIdx.x) * 256 + t);
        const float4* p = reinterpret_cast<const float4*>(x) + i * 2;
        float4 a = p[0], b = p[1];
        uint4 o;
        o.x = (unsigned)f2bf(a.x) | ((unsigned)f2bf(a.y) << 16);
        o.y = (unsigned)f2bf(a.z) | ((unsigned)f2bf(a.w) << 16);
        o.z = (unsigned)f2bf(b.x) | ((unsigned)f2bf(b.y) << 16);
        o.w = (unsigned)f2bf(b.z) | ((unsigned)f2bf(b.w) << 16);
        *reinterpret_cast<uint4*>(xb + i * 8) = o;
        if (chunk == 0 && blockIdx.y == 0 && blockIdx.x < 12) {
            int j = blockIdx.x * 256 + t;   // 0..3071
            float v = (j < 1024) ? bq[j] : (j < 2048 ? bk[j - 1024] : bv[j - 2048]);
            bias3[j] = v;
        }
    }
}

// ======== 3-buffer counted-vmcnt pipelined GEMM (T3+T4, asym tiles) =========
// (R14-verified. vmcnt(6) counted; see R14 derivation.)
#define GBAR8  asm volatile("s_barrier" ::: "memory")
#define LGKM0  asm volatile("s_waitcnt lgkmcnt(0)" ::: "memory")
#define VMC6   asm volatile("s_waitcnt vmcnt(6)" ::: "memory")
#define VMC0   asm volatile("s_waitcnt vmcnt(0)" ::: "memory")

#define STAGE8(bufp, off, srcp) do { \
    __builtin_amdgcn_global_load_lds( \
        (const __attribute__((address_space(1))) void*)(srcp), \
        (__attribute__((address_space(3))) void*)((bufp) + (off) + wv * 1024), 16, 0, 0); \
    __builtin_amdgcn_global_load_lds( \
        (const __attribute__((address_space(1))) void*)((srcp) + 65536), \
        (__attribute__((address_space(3))) void*)((bufp) + (off) + 8192 + wv * 1024), 16, 0, 0); \
} while (0)

#define LDA_ALL(Ab) do { \
    _Pragma("unroll") for (int m_ = 0; m_ < 4; ++m_) { \
        const int rl_ = wr * 64 + m_ * 16 + lj; \
        _Pragma("unroll") for (int k_ = 0; k_ < 2; ++k_) \
            af[m_][k_] = *reinterpret_cast<const bf16x8*>( \
                (Ab) + rl_ * 128 + (((k_ * 4 + lg) ^ (lj & 7)) * 16)); \
    } } while (0)

#define LDB_PAIR(Bb, pairi) do { \
    _Pragma("unroll") for (int n_ = 0; n_ < 2; ++n_) { \
        const int rl_ = wc * 64 + ((pairi) * 2 + n_) * 16 + lj; \
        _Pragma("unroll") for (int k_ = 0; k_ < 2; ++k_) \
            bfr[n_][k_] = *reinterpret_cast<const bf16x8*>( \
                (Bb) + rl_ * 128 + (((k_ * 4 + lg) ^ (lj & 7)) * 16)); \
    } } while (0)

#define MM_PAIR(npair) do { \
    __builtin_amdgcn_s_setprio(1); \
    _Pragma("unroll") for (int m_ = 0; m_ < 4; ++m_) \
        _Pragma("unroll") for (int n_ = 0; n_ < 2; ++n_) \
            _Pragma("unroll") for (int k_ = 0; k_ < 2; ++k_) \
                acc[m_][(npair) * 2 + n_] = \
                    __builtin_amdgcn_mfma_f32_16x16x32_bf16( \
                        af[m_][k_], bfr[n_][k_], acc[m_][(npair) * 2 + n_], 0, 0, 0); \
    __builtin_amdgcn_s_setprio(0); \
} while (0)

template<int BM, int BN, int OUTMODE>
__global__ __launch_bounds__(512)
void gemm_8ph3(const unsigned short* __restrict__ A,
               const unsigned short* __restrict__ BT,
               const float* __restrict__ bias,
               void* __restrict__ Cout, int N, int nScaled)
{
    constexpr int WN = BN / 64;
    constexpr bool A_SMALL = (BM == 128);
    constexpr int AOFF = 0;
    constexpr int BOFF = BM * 128;
    constexpr int SOFF   = A_SMALL ? AOFF : BOFF;
    constexpr int LLOOFF = A_SMALL ? BOFF : AOFF;
    constexpr int LHIOFF = LLOOFF + 16384;
    constexpr int BUFSZ  = (BM + BN) * 128;     // 49152 bytes

    __shared__ __align__(16) char lds8[3 * BUFSZ];   // 144 KB
    const int tid = threadIdx.x;
    const int nbn = N / BN;
    const int bid = blockIdx.x;
    const int wg  = (bid & 7) * ((int)gridDim.x >> 3) + (bid >> 3);  // XCD swizzle
    const int n0  = (wg % nbn) * BN;
    const int m0  = (wg / nbn) * BM;

    const int lane = tid & 63, wv = tid >> 6;
    const int wr = wv / WN, wc = wv % WN;
    const int lj = lane & 15, lg = lane >> 4;
    const int srow = tid >> 3;
    const int gsw  = 8 * ((tid & 7) ^ ((tid >> 3) & 7));

    const unsigned short* Sm  = A_SMALL ? A : BT;
    const int             sb  = A_SMALL ? m0 : n0;
    const unsigned short* Lm  = A_SMALL ? BT : A;
    const int             lb  = A_SMALL ? n0 : m0;
    const unsigned short* Ss  = Sm + (size_t)(sb + srow) * 1024 + gsw;
    const unsigned short* Llo = Lm + (size_t)(lb + srow) * 1024 + gsw;
    const unsigned short* Lhi = Lm + (size_t)(lb + 128 + srow) * 1024 + gsw;

    f32x4 acc[4][4];
    #pragma unroll
    for (int i = 0; i < 4; ++i)
        #pragma unroll
        for (int j = 0; j < 4; ++j) acc[i][j] = f32x4{0.f, 0.f, 0.f, 0.f};

    char* bufA = &lds8[0];
    char* bufB = &lds8[BUFSZ];
    char* bufC = &lds8[2 * BUFSZ];

    STAGE8(bufA, SOFF,   Ss);
    STAGE8(bufA, LLOOFF, Llo);
    STAGE8(bufA, LHIOFF, Lhi);
    STAGE8(bufB, SOFF,   Ss  + 64);
    STAGE8(bufB, LLOOFF, Llo + 64);
    STAGE8(bufB, LHIOFF, Lhi + 64);
    VMC6; GBAR8;

    bf16x8 af[4][2], bfr[2][2];

    for (int t = 0; t < 16; ++t) {
        const bool st = (t + 2) < 16;
        const int  t2 = (t + 2) * 64;

        LDA_ALL(bufA + AOFF); LDB_PAIR(bufA + BOFF, 0);
        if (st) {
            STAGE8(bufC, SOFF,   Ss  + t2);
            STAGE8(bufC, LLOOFF, Llo + t2);
        }
        GBAR8; LGKM0; MM_PAIR(0); GBAR8;

        LDB_PAIR(bufA + BOFF, 1);
        if (st) STAGE8(bufC, LHIOFF, Lhi + t2);
        GBAR8; LGKM0; MM_PAIR(1);
        if (st) { VMC6; } else { VMC0; }
        GBAR8;

        char* tmp = bufA; bufA = bufB; bufB = bufC; bufC = tmp;
    }

    const float sc = (OUTMODE == 0 && n0 < nScaled) ? SCALE_L2E : 1.0f;
    float bcol[4];
    #pragma unroll
    for (int nr = 0; nr < 4; ++nr) bcol[nr] = bias[n0 + wc * 64 + nr * 16 + lj];

    #pragma unroll
    for (int mr = 0; mr < 4; ++mr) {
        #pragma unroll
        for (int r4 = 0; r4 < 4; ++r4) {
            const int row = m0 + wr * 64 + mr * 16 + lg * 4 + r4;
            #pragma unroll
            for (int nr = 0; nr < 4; ++nr) {
                const int col = n0 + wc * 64 + nr * 16 + lj;
                float v = (acc[mr][nr][r4] + bcol[nr]) * sc;
                if (OUTMODE == 0)
                    reinterpret_cast<unsigned short*>(Cout)[(size_t)row * N + col] = f2bf(v);
                else
                    reinterpret_cast<float*>(Cout)[(size_t)row * N + col] = v;
            }
        }
    }
}

// ---------------- MFMA flash attention: K/V dbuf, ONE barrier/tile ----------
// R16-verified: 79.3us, VGPR 128 (exactly on the 128 allocation boundary).
// ANY +VGPR change regresses (R17: ones-MFMA +20 VGPR -> occupancy 18->10,
// dur +48%). DO NOT: min-waves bound (R8 spill), KVBLK=128 (R12 spill),
// 1024-block remap (R11 dispatch), 2-deep S (R6 regs), extra accumulators.
#define PV_STEP(m, T, rb) { \
    unsigned int w01 = cvtpk(T[(rb)+0], T[(rb)+1]); \
    unsigned int w23 = cvtpk(T[(rb)+2], T[(rb)+3]); \
    unsigned int w45 = cvtpk(T[(rb)+4], T[(rb)+5]); \
    unsigned int w67 = cvtpk(T[(rb)+6], T[(rb)+7]); \
    asm("v_permlane32_swap_b32 %0, %1" : "+v"(w01), "+v"(w45)); \
    asm("v_permlane32_swap_b32 %0, %1" : "+v"(w23), "+v"(w67)); \
    union { unsigned int u[4]; bf16x8 v; } pa; \
    pa.u[0] = w01; pa.u[1] = w23; pa.u[2] = w45; pa.u[3] = w67; \
    const int voff = (32 * (m) + 16 * hi) ^ lqswz; \
    bf16x8 va = *reinterpret_cast<const bf16x8*>(VTB + lq * 128 + voff); \
    bf16x8 vb = *reinterpret_cast<const bf16x8*>(VTB + (lq + 32) * 128 + voff); \
    y0 = __builtin_amdgcn_mfma_f32_32x32x16_bf16(va, pa.v, y0, 0, 0, 0); \
    y1 = __builtin_amdgcn_mfma_f32_32x32x16_bf16(vb, pa.v, y1, 0, 0, 0); \
}

#define VPACK() do { \
    pk[0] = __builtin_amdgcn_perm(vtb.x, vta.x, 0x05040100u); \
    pk[1] = __builtin_amdgcn_perm(vtb.x, vta.x, 0x07060302u); \
    pk[2] = __builtin_amdgcn_perm(vtb.y, vta.y, 0x05040100u); \
    pk[3] = __builtin_amdgcn_perm(vtb.y, vta.y, 0x07060302u); \
    pk[4] = __builtin_amdgcn_perm(vtb.z, vta.z, 0x05040100u); \
    pk[5] = __builtin_amdgcn_perm(vtb.z, vta.z, 0x07060302u); \
    pk[6] = __builtin_amdgcn_perm(vtb.w, vta.w, 0x05040100u); \
    pk[7] = __builtin_amdgcn_perm(vtb.w, vta.w, 0x07060302u); \
} while (0)

__global__ __launch_bounds__(256)
void attn_mfma6(const unsigned short* __restrict__ QKV, unsigned short* __restrict__ Yb)
{
    __shared__ __align__(16) char KV[2][16384];   // [buf][K 8KB | V^T 8KB]
    __shared__ unsigned short Ysc[4][32 * 72];    // per-wave [q][d], 144B stride

    const int tid = threadIdx.x, lane = tid & 63, wid = tid >> 6;
    const int lq = lane & 31, hi = lane >> 5;
    const int lqswz = (lq & 7) << 4;

    // XCD-grouped decomposition: id%8 == hb%8 -> same (h,b) shares an XCD
    const int id  = blockIdx.x;
    const int kk  = id >> 3;
    const int hb  = (id & 7) + 8 * (kk >> 3);
    const int pair = kk & 7;
    const int h = hb & 15, bz = hb >> 4;

    const size_t rowbase = (size_t)bz * TSEQ;
    const int hq = h * DHEAD, hk = 1024 + h * DHEAD, hv = 2048 + h * DHEAD;

    // staging thread mapping (constant per thread)
    const int krow = tid >> 3;           // K rows krow, krow+32
    const int kswz = ((tid & 7) * 16) ^ ((krow & 7) << 4);
    const int vk2  = 2 * (tid & 31);     // V key-pair
    const int vdg  = (tid >> 5) * 8;     // V d-group
    const int vkb  = vk2 * 2;            // byte offset of pair

    for (int iter = 0; iter < 2; ++iter) {
        const int qtile = iter ? (15 - pair) : pair;
        const int q0 = qtile * 128;
        const int wq = q0 + wid * 32;

        bf16x8 qf[4];                            // Q^T B-frags: d = 16s + 8hi + j
        {
            const unsigned short* qp = QKV + (rowbase + wq + lq) * QSTR + hq + hi * 8;
            #pragma unroll
            for (int s = 0; s < 4; ++s)
                qf[s] = *reinterpret_cast<const bf16x8*>(qp + s * 16);
        }
        f32x16 y0, y1;                           // Y^T tiles: d 0..31 / 32..63
        #pragma unroll
        for (int r = 0; r < 16; ++r) { y0[r] = 0.f; y1[r] = 0.f; }
        float mrow = NEG_BIG, lrow = 0.f;

        const int ktend = 2 * qtile + 2;

        // prefetch tile 0 into registers; pack V immediately (prologue only)
        uint4 kr0, kr1, vta, vtb;
        unsigned pk[8];
        {
            const unsigned short* kp = QKV + (rowbase + krow) * QSTR + hk + (tid & 7) * 8;
            kr0 = *reinterpret_cast<const uint4*>(kp);
            kr1 = *reinterpret_cast<const uint4*>(kp + 32 * QSTR);
            const unsigned short* vp = QKV + (rowbase + vk2) * QSTR + hv + vdg;
            vta = *reinterpret_cast<const uint4*>(vp);
            vtb = *reinterpret_cast<const uint4*>(vp + QSTR);
            VPACK();
        }

        for (int kt = 0; kt < ktend; ++kt) {
            char* KsB = &KV[kt & 1][0];
            char* VTB = &KV[kt & 1][8192];
            // ---- write prefetched regs -> buf[kt&1] (no pre-barrier: dbuf)
            *reinterpret_cast<uint4*>(KsB + krow * 128 + kswz) = kr0;
            *reinterpret_cast<uint4*>(KsB + (krow + 32) * 128 + kswz) = kr1;
            #pragma unroll
            for (int i2 = 0; i2 < 8; ++i2) {
                const int d = vdg + i2;
                *reinterpret_cast<unsigned*>(VTB + d * 128 + (vkb ^ ((d & 7) << 4))) = pk[i2];
            }
            __syncthreads();                     // single barrier per tile

            // ---- issue next tile's global loads (latency hides under compute)
            const bool more = (kt + 1 < ktend);
            if (more) {
                const unsigned short* kp = QKV + (rowbase + (kt + 1) * 64 + krow) * QSTR + hk + (tid & 7) * 8;
                kr0 = *reinterpret_cast<const uint4*>(kp);
                kr1 = *reinterpret_cast<const uint4*>(kp + 32 * QSTR);
                const unsigned short* vp = QKV + (rowbase + (kt + 1) * 64 + vk2) * QSTR + hv + vdg;
                vta = *reinterpret_cast<const uint4*>(vp);
                vtb = *reinterpret_cast<const uint4*>(vp + QSTR);
            }

            if (kt * 64 <= wq + 31) {            // tile intersects this wave's rows
                // ---- S^T = K Q^T (8 mfma 32x32x16); scale pre-folded into Q
                f32x16 s0, s1;
                #pragma unroll
                for (int r = 0; r < 16; ++r) { s0[r] = 0.f; s1[r] = 0.f; }
                #pragma unroll
                for (int s = 0; s < 4; ++s) {
                    const int off = (s * 32 + hi * 16) ^ lqswz;
                    bf16x8 k0 = *reinterpret_cast<const bf16x8*>(KsB + lq * 128 + off);
                    bf16x8 k1 = *reinterpret_cast<const bf16x8*>(KsB + (lq + 32) * 128 + off);
                    s0 = __builtin_amdgcn_mfma_f32_32x32x16_bf16(k0, qf[s], s0, 0, 0, 0);
                    s1 = __builtin_amdgcn_mfma_f32_32x32x16_bf16(k1, qf[s], s1, 0, 0, 0);
                }

                // ---- causal mask (diagonal tiles only)
                const bool diag = (kt * 64 + 63) > wq;
                if (diag) {
                    const int q_own = wq + lq;
                    #pragma unroll
                    for (int r = 0; r < 16; ++r) {
                        const int kl = kt * 64 + (r & 3) + 8 * (r >> 2) + 4 * hi;
                        if (kl > q_own) s0[r] = MASKVAL;
                        if (kl + 32 > q_own) s1[r] = MASKVAL;
                    }
                }

                // ---- tree row max + pair exchange
                float t8[8];
                #pragma unroll
                for (int r = 0; r < 8; ++r)
                    t8[r] = fmaxf(fmaxf(s0[r], s0[r + 8]), fmaxf(s1[r], s1[r + 8]));
                #pragma unroll
                for (int r = 0; r < 4; ++r) t8[r] = fmaxf(t8[r], t8[r + 4]);
                float pm = fmaxf(fmaxf(t8[0], t8[1]), fmaxf(t8[2], t8[3]));
                pm = fmaxf(pm, __shfl_xor(pm, 32));

                // ---- defer-max rescale (T13)
                if (__any(pm > mrow + DEFER_TH)) {
                    const float mnew = fmaxf(mrow, pm);
                    const float alpha = ex2(mrow - mnew);
                    #pragma unroll
                    for (int r = 0; r < 16; ++r) { y0[r] *= alpha; y1[r] *= alpha; }
                    lrow *= alpha;
                    mrow = mnew;
                }
                // ---- exp2 + tree row sum
                #pragma unroll
                for (int r = 0; r < 16; ++r) {
                    s0[r] = ex2(s0[r] - mrow);
                    s1[r] = ex2(s1[r] - mrow);
                }
                float a8[8];
                #pragma unroll
                for (int r = 0; r < 8; ++r) a8[r] = (s0[r] + s0[r + 8]) + (s1[r] + s1[r + 8]);
                #pragma unroll
                for (int r = 0; r < 4; ++r) a8[r] += a8[r + 4];
                float sum = (a8[0] + a8[1]) + (a8[2] + a8[3]);
                sum += __shfl_xor(sum, 32);
                lrow += sum;

                // ---- Y^T += V^T P^T (8 mfma)
                PV_STEP(0, s0, 0)
                PV_STEP(1, s0, 8)
                PV_STEP(2, s1, 0)
                PV_STEP(3, s1, 8)
            }

            // ---- pack next tile's V (load-waits satisfied; outside write window)
            if (more) VPACK();
        }

        // ---- epilogue: normalize, transpose via per-wave LDS, coalesced store
        {
            const float inv = 1.f / lrow;
            char* ysb = (char*)&Ysc[wid][0];
            #pragma unroll
            for (int t = 0; t < 8; ++t) {
                const int dl = ((2 * t) & 3) + 8 * (t >> 1) + 4 * hi;
                unsigned int wa = cvtpk(y0[2 * t] * inv, y0[2 * t + 1] * inv);
                unsigned int wb = cvtpk(y1[2 * t] * inv, y1[2 * t + 1] * inv);
                *reinterpret_cast<unsigned int*>(ysb + lq * 144 + dl * 2) = wa;
                *reinterpret_cast<unsigned int*>(ysb + lq * 144 + (dl + 32) * 2) = wb;
            }
            #pragma unroll
            for (int u = 0; u < 4; ++u) {
                const int rr = lane >> 1, ch = (lane & 1) + 2 * u;
                uint4 val = *reinterpret_cast<const uint4*>(ysb + rr * 144 + ch * 16);
                *reinterpret_cast<uint4*>(Yb + (rowbase + q0 + wid * 32 + rr) * CDIM + h * DHEAD + ch * 8) = val;
            }
        }
    }
}

// ---------------------------------------------------------------------------
extern "C" void kernel_launch(void* const* d_in, const int* in_sizes, int n_in,
                              void* d_out, int out_size, void* d_ws, size_t ws_size,
                              hipStream_t stream)
{
    const float* x  = (const float*)d_in[0];
    const float* Wk = (const float*)d_in[1];
    const float* bk = (const float*)d_in[2];
    const float* Wq = (const float*)d_in[3];
    const float* bq = (const float*)d_in[4];
    const float* Wv = (const float*)d_in[5];
    const float* bv = (const float*)d_in[6];
    const float* Wp = (const float*)d_in[7];
    const float* bp = (const float*)d_in[8];

    const size_t xe = (size_t)MROWS * CDIM;   // 8,388,608
    const size_t we = (size_t)CDIM * CDIM;    // 1,048,576
    unsigned short* xb    = (unsigned short*)d_ws;
    unsigned short* wqkvt = xb + xe;          // [3072][1024] = Wq^T|Wk^T|Wv^T
    unsigned short* wpt   = wqkvt + 3 * we;
    unsigned short* qkv   = wpt + we;         // [8192][3072] bf16
    unsigned short* ab    = qkv + (size_t)MROWS * QSTR;
    float*          bias3 = (float*)(ab + xe);

    // fused prep: x->bf16, W^T x4, bias concat (one launch)
    prep_kernel<<<dim3(32, 32, 8), 256, 0, stream>>>(
        x, Wq, Wk, Wv, Wp, bq, bk, bv,
        xb, wqkvt, wqkvt + we, wqkvt + 2 * we, wpt, bias3);

    // fused QKV projection: 128x256 3-buf counted pipeline, 768 blocks (3 rounds)
    gemm_8ph3<128, 256, 0><<<768, 512, 0, stream>>>(xb, wqkvt, bias3, qkv,
                                                    QSTR, 1024);

    attn_mfma6<<<512, 256, 0, stream>>>(qkv, ab);

    // output projection -> fp32: 256x128 3-buf counted pipeline, 256 blocks (1 round)
    gemm_8ph3<256, 128, 1><<<256, 512, 0, stream>>>(ab, wpt, bp, d_out,
                                                    CDIM, 0);
}